// Round 6
// baseline (149.261 us; speedup 1.0000x reference)
//
#include <hip/hip_runtime.h>
#include <hip/hip_bf16.h>

#define EPS 1e-6f

constexpr int B = 64;
constexpr int NPB = 512 * 512;                 // 262144 elements per batch
constexpr int THREADS = 256;                   // 4 waves per block
constexpr int WPB = THREADS / 64;              // waves per block
constexpr int BLOCKS_PER_BATCH = 16;
constexpr int NBLK = B * BLOCKS_PER_BATCH;     // 1024 blocks = 4 per CU (persistent)
constexpr int ELEM_PER_BLOCK = NPB / BLOCKS_PER_BATCH;   // 16384
constexpr int ELEM_PER_WAVE = ELEM_PER_BLOCK / WPB;      // 4096
constexpr int CHUNK = 512;                     // elements per chunk per wave (per array)
constexpr int NCHUNK = ELEM_PER_WAVE / CHUNK;  // 8
constexpr int NW = NBLK * WPB;                 // 4096 wave partials

__device__ __forceinline__ float waveReduce(float v) {
    #pragma unroll
    for (int off = 32; off > 0; off >>= 1) v += __shfl_down(v, off, 64);
    return v;
}

__device__ __forceinline__ void stage16(const float* g, float* l) {
    // lane i's 16B lands at LDS base + i*16 (wave-uniform LDS base)
    __builtin_amdgcn_global_load_lds(
        (const __attribute__((address_space(1))) void*)g,
        (__attribute__((address_space(3))) void*)l, 16, 0, 0);
}

// Persistent wave-autonomous pipeline: each wave double-buffers its private
// 8KB LDS slice via async DMA, fine-grained vmcnt(4) keeps the queue full,
// NO barriers anywhere in the loop.
__global__ __launch_bounds__(THREADS) void kl_partial(
        const float* __restrict__ pred, const float* __restrict__ truem,
        float* __restrict__ ws) {
    // [wave][buf][0..511]=pred chunk, [512..1023]=true chunk  -> 32 KB total
    __shared__ float lds[WPB][2][2 * CHUNK];

    const int wave = threadIdx.x >> 6;
    const int lane = threadIdx.x & 63;
    const size_t wbase = (size_t)blockIdx.x * ELEM_PER_BLOCK
                       + (size_t)wave * ELEM_PER_WAVE;
    const float* gp = pred + wbase;
    const float* gt = truem + wbase;

    float sp = 0.f, st = 0.f, s = 0.f;

    auto issue = [&](int c) {
        const float* p = gp + c * CHUNK;
        const float* t = gt + c * CHUNK;
        float* lp = &lds[wave][c & 1][0];
        float* lt = &lds[wave][c & 1][CHUNK];
        stage16(p + lane * 4,       lp);
        stage16(p + 256 + lane * 4, lp + 256);
        stage16(t + lane * 4,       lt);
        stage16(t + 256 + lane * 4, lt + 256);
    };

    auto compute = [&](int c) {
        const float4* p4 = (const float4*)&lds[wave][c & 1][0];
        const float4* t4 = (const float4*)&lds[wave][c & 1][CHUNK];
        #pragma unroll
        for (int j = 0; j < 2; ++j) {
            float4 p = p4[lane + j * 64];
            float4 t = t4[lane + j * 64];
            // raw sums; per-element +EPS folded analytically in kl_final
            sp += (p.x + p.y) + (p.z + p.w);
            st += (t.x + t.y) + (t.z + t.w);
            float px = p.x + EPS, py = p.y + EPS, pz = p.z + EPS, pw = p.w + EPS;
            float tx = t.x + EPS, ty = t.y + EPS, tz = t.z + EPS, tw = t.w + EPS;
            s += tx * (__logf(tx) - __logf(px));
            s += ty * (__logf(ty) - __logf(py));
            s += tz * (__logf(tz) - __logf(pz));
            s += tw * (__logf(tw) - __logf(pw));
        }
    };

    issue(0);
    #pragma unroll
    for (int c = 1; c < NCHUNK; ++c) {
        issue(c);
        // older chunk's 4 DMA ops retired; the 4 just issued stay in flight
        asm volatile("s_waitcnt vmcnt(4)" ::: "memory");
        compute(c - 1);
    }
    asm volatile("s_waitcnt vmcnt(0)" ::: "memory");
    compute(NCHUNK - 1);

    sp = waveReduce(sp);
    st = waveReduce(st);
    s  = waveReduce(s);
    if (lane == 0) {
        const int idx = blockIdx.x * WPB + wave;   // batch = idx/64
        ws[idx]          = sp;   // Sp partial (without eps)
        ws[NW + idx]     = st;   // St partial (without eps)
        ws[2 * NW + idx] = s;    // S partial
    }
}

// Combine 64 wave-partials per batch, fold the analytic N*eps, mean over B.
__global__ __launch_bounds__(256) void kl_final(
        const float* __restrict__ ws, float* __restrict__ out) {
    const int b = threadIdx.x & 63;   // batch
    const int q = threadIdx.x >> 6;   // quarter 0..3
    float Sp = 0.f, St = 0.f, S = 0.f;
    #pragma unroll
    for (int k = 0; k < 16; ++k) {
        const int idx = b * 64 + q * 16 + k;
        Sp += ws[idx];
        St += ws[NW + idx];
        S  += ws[2 * NW + idx];
    }
    __shared__ float r[3][4][64];
    r[0][q][b] = Sp; r[1][q][b] = St; r[2][q][b] = S;
    __syncthreads();
    if (threadIdx.x < 64) {
        const int bb = threadIdx.x;
        float sp = 0.f, stt = 0.f, ss = 0.f;
        #pragma unroll
        for (int qq = 0; qq < 4; ++qq) {
            sp += r[0][qq][bb]; stt += r[1][qq][bb]; ss += r[2][qq][bb];
        }
        const float epsN = (float)NPB * EPS;
        sp += epsN; stt += epsN;
        float kl = ss / stt + logf(sp / stt);
        kl = waveReduce(kl);
        if (bb == 0) out[0] = kl * (1.0f / B);
    }
}

extern "C" void kernel_launch(void* const* d_in, const int* in_sizes, int n_in,
                              void* d_out, int out_size, void* d_ws, size_t ws_size,
                              hipStream_t stream) {
    const float* pred  = (const float*)d_in[0];
    const float* truem = (const float*)d_in[1];
    float* out = (float*)d_out;
    float* ws  = (float*)d_ws;

    kl_partial<<<NBLK, THREADS, 0, stream>>>(pred, truem, ws);
    kl_final<<<1, 256, 0, stream>>>(ws, out);
}

// Round 8
// 137.697 us; speedup vs baseline: 1.0840x; 1.0840x over previous
//
#include <hip/hip_runtime.h>
#include <hip/hip_bf16.h>

#define EPS 1e-6f

typedef float f4 __attribute__((ext_vector_type(4)));   // native vec: OK for nontemporal builtin

constexpr int B = 64;
constexpr int NPB = 512 * 512;                     // elements per batch = 262144
constexpr int BLOCKS_PER_BATCH = 32;
constexpr int NBLK = B * BLOCKS_PER_BATCH;         // 2048 blocks
constexpr int THREADS = 256;
constexpr int CHUNK = NPB / BLOCKS_PER_BATCH;      // 8192 elements per block
constexpr int ITERS = CHUNK / 4 / THREADS;         // 8 float4-pairs per thread

__device__ __forceinline__ float waveReduce(float v) {
    #pragma unroll
    for (int off = 32; off > 0; off >>= 1) v += __shfl_down(v, off, 64);
    return v;
}

// Kernel 1: per-block partial sums of (Sp, St, S). Nontemporal float4 loads:
// probe whether the L2/L3 retention path (dirty lines from the harness's
// input-restore) is the ~3.1 TB/s service ceiling.
__global__ __launch_bounds__(THREADS) void kl_partial(
        const float* __restrict__ pred, const float* __restrict__ truem,
        float* __restrict__ ws) {
    const size_t base = (size_t)blockIdx.x * CHUNK;
    const f4* p4 = (const f4*)(pred + base);
    const f4* t4 = (const f4*)(truem + base);

    float sp = 0.f, st = 0.f, s = 0.f;
    #pragma unroll
    for (int j = 0; j < ITERS; ++j) {
        f4 p = __builtin_nontemporal_load(&p4[threadIdx.x + j * THREADS]);
        f4 t = __builtin_nontemporal_load(&t4[threadIdx.x + j * THREADS]);
        // raw sums; the per-element +EPS is folded analytically in kl_final
        sp += (p.x + p.y) + (p.z + p.w);
        st += (t.x + t.y) + (t.z + t.w);
        float px = p.x + EPS, py = p.y + EPS, pz = p.z + EPS, pw = p.w + EPS;
        float tx = t.x + EPS, ty = t.y + EPS, tz = t.z + EPS, tw = t.w + EPS;
        s += tx * (__logf(tx) - __logf(px));
        s += ty * (__logf(ty) - __logf(py));
        s += tz * (__logf(tz) - __logf(pz));
        s += tw * (__logf(tw) - __logf(pw));
    }

    sp = waveReduce(sp);
    st = waveReduce(st);
    s  = waveReduce(s);

    __shared__ float red[3][THREADS / 64];
    const int wave = threadIdx.x >> 6;
    const int lane = threadIdx.x & 63;
    if (lane == 0) { red[0][wave] = sp; red[1][wave] = st; red[2][wave] = s; }
    __syncthreads();
    if (threadIdx.x == 0) {
        float a0 = 0.f, a1 = 0.f, a2 = 0.f;
        #pragma unroll
        for (int w = 0; w < THREADS / 64; ++w) {
            a0 += red[0][w]; a1 += red[1][w]; a2 += red[2][w];
        }
        ws[blockIdx.x]            = a0;   // Sp partial (without eps)
        ws[NBLK + blockIdx.x]     = a1;   // St partial (without eps)
        ws[2 * NBLK + blockIdx.x] = a2;   // S partial
    }
}

// Kernel 2: sum 32 partials per batch, add the analytic N*eps term, combine.
__global__ __launch_bounds__(64) void kl_final(
        const float* __restrict__ ws, float* __restrict__ out) {
    const int b = threadIdx.x;   // one wave, one batch per lane
    float Sp = 0.f, St = 0.f, S = 0.f;
    #pragma unroll
    for (int k = 0; k < BLOCKS_PER_BATCH; ++k) {
        const int idx = b * BLOCKS_PER_BATCH + k;
        Sp += ws[idx];
        St += ws[NBLK + idx];
        S  += ws[2 * NBLK + idx];
    }
    const float epsN = (float)NPB * EPS;   // sum of the per-element +EPS
    Sp += epsN;
    St += epsN;
    float kl = S / St + logf(Sp / St);
    kl = waveReduce(kl);
    if (b == 0) out[0] = kl * (1.0f / B);
}

extern "C" void kernel_launch(void* const* d_in, const int* in_sizes, int n_in,
                              void* d_out, int out_size, void* d_ws, size_t ws_size,
                              hipStream_t stream) {
    const float* pred  = (const float*)d_in[0];
    const float* truem = (const float*)d_in[1];
    float* out = (float*)d_out;
    float* ws  = (float*)d_ws;

    kl_partial<<<NBLK, THREADS, 0, stream>>>(pred, truem, ws);
    kl_final<<<1, 64, 0, stream>>>(ws, out);
}

// Round 9
// 136.461 us; speedup vs baseline: 1.0938x; 1.0091x over previous
//
#include <hip/hip_runtime.h>
#include <hip/hip_bf16.h>

#define EPS 1e-6f
#define LN2 0.6931471805599453f

typedef float f4 __attribute__((ext_vector_type(4)));

constexpr int B = 64;
constexpr int NPB = 512 * 512;                     // elements per batch = 262144
constexpr int BLOCKS_PER_BATCH = 16;
constexpr int NBLK = B * BLOCKS_PER_BATCH;         // 1024 blocks = 4/CU
constexpr int THREADS = 256;
constexpr int CHUNK = NPB / BLOCKS_PER_BATCH;      // 16384 elements per block
constexpr int ITERS = CHUNK / 4 / THREADS;         // 16 float4-pairs per thread

__device__ __forceinline__ float waveReduce(float v) {
    #pragma unroll
    for (int off = 32; off > 0; off >>= 1) v += __shfl_down(v, off, 64);
    return v;
}

// Kernel 1: per-block partials (Sp, St, S2 = sum (t+e)*(log2(t+e)-log2(p+e))).
// nt loads (L3-retention bypass) + depth-2 rotating register pipeline: the
// cur=next rotation forces one load-pair in flight under every compute phase,
// breaking the convoy (load -> vmcnt(0) -> compute) serialization.
__global__ __launch_bounds__(THREADS) void kl_partial(
        const float* __restrict__ pred, const float* __restrict__ truem,
        float* __restrict__ ws) {
    const size_t base = (size_t)blockIdx.x * CHUNK;
    const f4* p4 = (const f4*)(pred + base);
    const f4* t4 = (const f4*)(truem + base);

    float sp = 0.f, st = 0.f, s = 0.f;

    f4 pc = __builtin_nontemporal_load(&p4[threadIdx.x]);
    f4 tc = __builtin_nontemporal_load(&t4[threadIdx.x]);
    #pragma unroll
    for (int j = 1; j <= ITERS; ++j) {
        f4 pn, tn;
        if (j < ITERS) {
            pn = __builtin_nontemporal_load(&p4[threadIdx.x + j * THREADS]);
            tn = __builtin_nontemporal_load(&t4[threadIdx.x + j * THREADS]);
        }
        // consume cur while next is in flight
        sp += (pc.x + pc.y) + (pc.z + pc.w);
        st += (tc.x + tc.y) + (tc.z + tc.w);
        float px = pc.x + EPS, py = pc.y + EPS, pz = pc.z + EPS, pw = pc.w + EPS;
        float tx = tc.x + EPS, ty = tc.y + EPS, tz = tc.z + EPS, tw = tc.w + EPS;
        s += tx * (__log2f(tx) - __log2f(px));
        s += ty * (__log2f(ty) - __log2f(py));
        s += tz * (__log2f(tz) - __log2f(pz));
        s += tw * (__log2f(tw) - __log2f(pw));
        pc = pn; tc = tn;
    }

    sp = waveReduce(sp);
    st = waveReduce(st);
    s  = waveReduce(s);

    __shared__ float red[3][THREADS / 64];
    const int wave = threadIdx.x >> 6;
    const int lane = threadIdx.x & 63;
    if (lane == 0) { red[0][wave] = sp; red[1][wave] = st; red[2][wave] = s; }
    __syncthreads();
    if (threadIdx.x == 0) {
        float a0 = 0.f, a1 = 0.f, a2 = 0.f;
        #pragma unroll
        for (int w = 0; w < THREADS / 64; ++w) {
            a0 += red[0][w]; a1 += red[1][w]; a2 += red[2][w];
        }
        ws[blockIdx.x]            = a0;   // Sp partial (without eps)
        ws[NBLK + blockIdx.x]     = a1;   // St partial (without eps)
        ws[2 * NBLK + blockIdx.x] = a2;   // S partial, log2 units
    }
}

// Kernel 2: sum 16 partials per batch, fold eps + ln2, mean over B.
__global__ __launch_bounds__(64) void kl_final(
        const float* __restrict__ ws, float* __restrict__ out) {
    const int b = threadIdx.x;   // one wave, one batch per lane
    float Sp = 0.f, St = 0.f, S = 0.f;
    #pragma unroll
    for (int k = 0; k < BLOCKS_PER_BATCH; ++k) {
        const int idx = b * BLOCKS_PER_BATCH + k;
        Sp += ws[idx];
        St += ws[NBLK + idx];
        S  += ws[2 * NBLK + idx];
    }
    const float epsN = (float)NPB * EPS;   // sum of the per-element +EPS
    Sp += epsN;
    St += epsN;
    float kl = (S * LN2) / St + logf(Sp / St);
    kl = waveReduce(kl);
    if (b == 0) out[0] = kl * (1.0f / B);
}

extern "C" void kernel_launch(void* const* d_in, const int* in_sizes, int n_in,
                              void* d_out, int out_size, void* d_ws, size_t ws_size,
                              hipStream_t stream) {
    const float* pred  = (const float*)d_in[0];
    const float* truem = (const float*)d_in[1];
    float* out = (float*)d_out;
    float* ws  = (float*)d_ws;

    kl_partial<<<NBLK, THREADS, 0, stream>>>(pred, truem, ws);
    kl_final<<<1, 64, 0, stream>>>(ws, out);
}